// Round 6
// baseline (414.798 us; speedup 1.0000x reference)
//
#include <hip/hip_runtime.h>
#include <hip/hip_bf16.h>

// ForcedDAGPlanner: B=16,S=4096,E=1024,M=64,N=32,H=8,D=128
//   scores[b,h,s] = x[b,s,:]·qk[h,:] + qb[h]   (qk = (q·Wk)/sqrt(D), 8x1024)
//   xa[b,h,:]     = softmax_s-weighted sum of x rows (unnormalized partials + l)
//   ctx[b,j]      = xa[b,h(j),:]·wv[j,:] + bv[j]
//   k_nodes = 32 -> node_mask all-true.
// R6: (1) k_fused v4 — 4 waves = {2 row-halves}x{2 head-groups}: x read once per
// row-half, 2x L1 amplification (was 8x); LDS combine of row-halves.
// (2) one per-batch mega-tail kernel (16 blk x 1024 thr) replaces 6 kernels.

#define DEVFN __device__ __forceinline__

constexpr float SCALE = 0.08838834764831845f; // 1/sqrt(128)

// workspace offsets (floats)
constexpr size_t OFF_QVEC  = 0;        // 1024
constexpr size_t OFF_QKT   = 1024;     // 8192  [h*1024+e]
constexpr size_t OFF_QB    = 9216;     // 8
constexpr size_t OFF_LPART = 9224;     // 4096  [cid*8+h]
constexpr size_t OFF_XA    = 13320;    // 131072 [bh*1024+e]
constexpr size_t OFF_PART  = 144392;   // 512*8*1024 = 4194304 [cid][h][e]
// total ~17.4 MB of d_ws

// output offsets (f32 elements)
constexpr size_t OUT_EMB  = 0;        // 16*32*1024
constexpr size_t OUT_ADJ  = 524288;   // 16*32*32
constexpr size_t OUT_SURF = 540672;   // 16
constexpr size_t OUT_CPLX = 540688;   // 16*32
constexpr size_t OUT_MASK = 541200;   // 16*32

DEVFN float gelu_exact(float x) {
  return 0.5f * x * (1.0f + erff(x * 0.70710678118654752f));
}
DEVFN float softplus_f(float x) {
  return fmaxf(x, 0.0f) + log1pf(expf(-fabsf(x)));
}
DEVFN float dot4(float4 a, float4 b) {
  return a.x * b.x + a.y * b.y + a.z * b.z + a.w * b.w;
}

// ---- K0: qvec[i] = task_query · wq[i,:] + bq[i]   (wave per output)
__global__ void k_qvec(const float* __restrict__ tq, const float* __restrict__ wq,
                       const float* __restrict__ bq, float* __restrict__ qvec) {
  int wid = threadIdx.x >> 6, lane = threadIdx.x & 63;
  int i = blockIdx.x * 4 + wid;  // 256 blocks -> 1024 outputs
  const float* wrow = wq + (size_t)i * 1024;
  float acc = 0.f;
#pragma unroll
  for (int k = 0; k < 4; ++k) {
    int e = lane * 4 + k * 256;
    acc += dot4(*(const float4*)(tq + e), *(const float4*)(wrow + e));
  }
#pragma unroll
  for (int off = 32; off; off >>= 1) acc += __shfl_xor(acc, off);
  if (lane == 0) qvec[i] = acc + bq[i];
}

// ---- K0b: qkT[h*1024+e] = SCALE * sum_d qvec[h*128+d]*wk[(h*128+d)*1024+e]; qb[h]
__global__ void k_qk(const float* __restrict__ qvec, const float* __restrict__ wk,
                     const float* __restrict__ bk, float* __restrict__ qkT,
                     float* __restrict__ qb) {
  __shared__ float qh[128];
  int h = blockIdx.x >> 2, e0 = (blockIdx.x & 3) * 256;  // 32 blocks
  int t = threadIdx.x;
  if (t < 128) qh[t] = qvec[h * 128 + t];
  __syncthreads();
  int e = e0 + t;
  float acc = 0.f;
#pragma unroll 32
  for (int d = 0; d < 128; ++d)
    acc += qh[d] * wk[(size_t)(h * 128 + d) * 1024 + e];
  qkT[h * 1024 + e] = acc * SCALE;
  if (t == 0 && e0 == 0) {
    float s = 0.f;
    for (int d = 0; d < 128; ++d) s += qh[d] * bk[h * 128 + d];
    qb[h] = s * SCALE;
  }
}

// ---- K1 v4: fused score+exp+weighted-sum, single x pass.
// 512 blocks x 256 threads. wid = rh*2+hg is wrong order; use rh=wid>>1, hg=wid&1:
// waves (rh,hg): rows [rh*64, rh*64+64), heads [hg*4, hg*4+4). Each row read by
// 2 waves (hg=0,1) -> 2x L1 amplification. Row-halves combined in LDS.
__global__ __launch_bounds__(256, 2) void k_fused(
    const float* __restrict__ x, const float* __restrict__ qkT,
    const float* __restrict__ qb, float* __restrict__ partial,
    float* __restrict__ lpart) {
  __shared__ __align__(16) float lds[8 * 1024];
  __shared__ float s_ll[8];
  int t = threadIdx.x, wid = t >> 6, lane = t & 63;
  int rh = wid >> 1, hg = wid & 1;

  float4 qr[4][4];
#pragma unroll
  for (int hh = 0; hh < 4; ++hh)
#pragma unroll
    for (int k = 0; k < 4; ++k)
      qr[hh][k] = *(const float4*)(qkT + (hg * 4 + hh) * 1024 + k * 256 + lane * 4);
  float qbr[4];
#pragma unroll
  for (int hh = 0; hh < 4; ++hh) qbr[hh] = qb[hg * 4 + hh];

  float4 acc[4][4];
#pragma unroll
  for (int hh = 0; hh < 4; ++hh)
#pragma unroll
    for (int k = 0; k < 4; ++k) acc[hh][k] = make_float4(0.f, 0.f, 0.f, 0.f);
  float lsum[4] = {0.f, 0.f, 0.f, 0.f};

  int row0 = blockIdx.x * 128 + rh * 64;
  const float* xr = x + ((size_t)row0 << 10) + lane * 4;
  float4 A0 = *(const float4*)(xr + 0);
  float4 A1 = *(const float4*)(xr + 256);
  float4 A2 = *(const float4*)(xr + 512);
  float4 A3 = *(const float4*)(xr + 768);
  float4 B0 = *(const float4*)(xr + 1024);
  float4 B1 = *(const float4*)(xr + 1280);
  float4 B2 = *(const float4*)(xr + 1536);
  float4 B3 = *(const float4*)(xr + 1792);

  for (int r = 0; r < 64; ++r) {
    float4 c0 = A0, c1 = A1, c2 = A2, c3 = A3;
    A0 = B0; A1 = B1; A2 = B2; A3 = B3;
    if (r < 62) {
      const float* nx = xr + ((size_t)(r + 2) << 10);
      B0 = *(const float4*)(nx + 0);
      B1 = *(const float4*)(nx + 256);
      B2 = *(const float4*)(nx + 512);
      B3 = *(const float4*)(nx + 768);
    }
    float s[4];
#pragma unroll
    for (int hh = 0; hh < 4; ++hh)
      s[hh] = dot4(c0, qr[hh][0]) + dot4(c1, qr[hh][1]) +
              dot4(c2, qr[hh][2]) + dot4(c3, qr[hh][3]);
#pragma unroll
    for (int off = 1; off <= 32; off <<= 1)
#pragma unroll
      for (int hh = 0; hh < 4; ++hh) s[hh] += __shfl_xor(s[hh], off);
    float w[4];
#pragma unroll
    for (int hh = 0; hh < 4; ++hh) {
      w[hh] = expf(s[hh] + qbr[hh]);
      lsum[hh] += w[hh];
    }
#pragma unroll
    for (int hh = 0; hh < 4; ++hh) {
      acc[hh][0].x += w[hh] * c0.x; acc[hh][0].y += w[hh] * c0.y;
      acc[hh][0].z += w[hh] * c0.z; acc[hh][0].w += w[hh] * c0.w;
      acc[hh][1].x += w[hh] * c1.x; acc[hh][1].y += w[hh] * c1.y;
      acc[hh][1].z += w[hh] * c1.z; acc[hh][1].w += w[hh] * c1.w;
      acc[hh][2].x += w[hh] * c2.x; acc[hh][2].y += w[hh] * c2.y;
      acc[hh][2].z += w[hh] * c2.z; acc[hh][2].w += w[hh] * c2.w;
      acc[hh][3].x += w[hh] * c3.x; acc[hh][3].y += w[hh] * c3.y;
      acc[hh][3].z += w[hh] * c3.z; acc[hh][3].w += w[hh] * c3.w;
    }
  }
  // combine the two row-halves per head
  if (rh == 1) {
#pragma unroll
    for (int hh = 0; hh < 4; ++hh)
#pragma unroll
      for (int k = 0; k < 4; ++k)
        *(float4*)(lds + (hg * 4 + hh) * 1024 + k * 256 + lane * 4) = acc[hh][k];
    if (lane == 0)
#pragma unroll
      for (int hh = 0; hh < 4; ++hh) s_ll[hg * 4 + hh] = lsum[hh];
  }
  __syncthreads();
  if (rh == 0) {
    size_t base = (((size_t)blockIdx.x * 8 + hg * 4) << 10) + lane * 4;
#pragma unroll
    for (int hh = 0; hh < 4; ++hh)
#pragma unroll
      for (int k = 0; k < 4; ++k) {
        const float4 o = *(const float4*)(lds + (hg * 4 + hh) * 1024 + k * 256 + lane * 4);
        float4 v = acc[hh][k];
        v.x += o.x; v.y += o.y; v.z += o.z; v.w += o.w;
        *(float4*)(partial + base + ((size_t)hh << 10) + k * 256) = v;
      }
    if (lane == 0)
#pragma unroll
      for (int hh = 0; hh < 4; ++hh)
        lpart[blockIdx.x * 8 + hg * 4 + hh] = lsum[hh] + s_ll[hg * 4 + hh];
  }
}

// ---- K2: xa[b,h,e] = (sum_{c<32} partial[b*32+c][h][e]) / (sum_c l)
__global__ void k_comb2(const float* __restrict__ partial,
                        const float* __restrict__ lpart,
                        float* __restrict__ xa) {
  __shared__ float sl;
  int bh = blockIdx.x, b = bh >> 3, h = bh & 7, t = threadIdx.x;
  if (t == 0) {
    float s = 0.f;
#pragma unroll
    for (int c = 0; c < 32; ++c) s += lpart[(b * 32 + c) * 8 + h];
    sl = 1.0f / s;
  }
  __syncthreads();
  float linv = sl;
  float4 s4 = make_float4(0.f, 0.f, 0.f, 0.f);
#pragma unroll 8
  for (int c = 0; c < 32; ++c) {
    float4 v = *(const float4*)(partial +
        (((size_t)(b * 32 + c) * 8 + h) << 10) + t * 4);
    s4.x += v.x; s4.y += v.y; s4.z += v.z; s4.w += v.w;
  }
  s4.x *= linv; s4.y *= linv; s4.z *= linv; s4.w *= linv;
  *(float4*)(xa + ((size_t)bh << 10) + t * 4) = s4;
}

// ---- K3: per-batch mega-tail. 16 blocks x 1024 threads (16 waves).
// xa -> ctx -> trep -> tm -> LN -> h2 -> nm_pre -> LN -> {heads, nemb}
__global__ __launch_bounds__(1024) void k_tail(
    const float* __restrict__ xa, const float* __restrict__ wv,
    const float* __restrict__ bv, const float* __restrict__ wo,
    const float* __restrict__ bo, const float* __restrict__ mp_w,
    const float* __restrict__ mp_b, const float* __restrict__ ln_w,
    const float* __restrict__ ln_b, const float* __restrict__ ng_w1,
    const float* __restrict__ ng_b1, const float* __restrict__ ng_w2,
    const float* __restrict__ ng_b2, const float* __restrict__ ep_w,
    const float* __restrict__ ep_b, const float* __restrict__ cp_w1,
    const float* __restrict__ cp_b1, const float* __restrict__ cp_w2,
    const float* __restrict__ cp_b2, const float* __restrict__ np_w,
    const float* __restrict__ np_b, float* __restrict__ out) {
  __shared__ __align__(16) float s_xa[8192];
  __shared__ __align__(16) float s_ctx[1024];
  __shared__ __align__(16) float s_tr[1024];
  __shared__ float s_tm[64];
  __shared__ float s_h2[128];
  __shared__ __align__(16) float s_nm[2048];
  __shared__ float s_t[2048];
  __shared__ float s_c1[1024];
  __shared__ float s_cx[32];
  int b = blockIdx.x, t = threadIdx.x, wid = t >> 6, lane = t & 63;

  // stage in xa (32 KB)
#pragma unroll
  for (int i = 0; i < 2; ++i)
    *(float4*)(s_xa + (t + i * 1024) * 4) =
        *(const float4*)(xa + ((size_t)b << 13) + (t + i * 1024) * 4);
  __syncthreads();

  // ctx: 1024 wave-dots (64 per wave)
  for (int it = 0; it < 64; ++it) {
    int j = wid * 64 + it;
    int h = j >> 7;
    const float* wr = wv + (size_t)j * 1024 + lane * 4;
    const float* xr = s_xa + h * 1024 + lane * 4;
    float acc = 0.f;
#pragma unroll
    for (int k = 0; k < 4; ++k)
      acc += dot4(*(const float4*)(xr + k * 256), *(const float4*)(wr + k * 256));
#pragma unroll
    for (int off = 32; off; off >>= 1) acc += __shfl_xor(acc, off);
    if (lane == 0) s_ctx[j] = acc + bv[j];
  }
  __syncthreads();

  // trep: 1024 wave-dots over ctx
  for (int it = 0; it < 64; ++it) {
    int i = wid * 64 + it;
    const float* wr = wo + (size_t)i * 1024 + lane * 4;
    const float* xr = s_ctx + lane * 4;
    float acc = 0.f;
#pragma unroll
    for (int k = 0; k < 4; ++k)
      acc += dot4(*(const float4*)(xr + k * 256), *(const float4*)(wr + k * 256));
#pragma unroll
    for (int off = 32; off; off >>= 1) acc += __shfl_xor(acc, off);
    if (lane == 0) s_tr[i] = acc + bo[i];
  }
  __syncthreads();

  // tm: 64 wave-dots (4 per wave)
  for (int it = 0; it < 4; ++it) {
    int m = wid * 4 + it;
    const float* wr = mp_w + (size_t)m * 1024 + lane * 4;
    const float* xr = s_tr + lane * 4;
    float acc = 0.f;
#pragma unroll
    for (int k = 0; k < 4; ++k)
      acc += dot4(*(const float4*)(xr + k * 256), *(const float4*)(wr + k * 256));
#pragma unroll
    for (int off = 32; off; off >>= 1) acc += __shfl_xor(acc, off);
    if (lane == 0) s_tm[m] = acc + mp_b[m];
  }
  __syncthreads();

  // LN over 64 (wave 0)
  if (wid == 0) {
    float v = s_tm[lane];
    float sm = v;
#pragma unroll
    for (int off = 32; off; off >>= 1) sm += __shfl_xor(sm, off);
    float mu = sm * (1.f / 64.f);
    float d = v - mu;
    float vv = d * d;
#pragma unroll
    for (int off = 32; off; off >>= 1) vv += __shfl_xor(vv, off);
    float rstd = 1.f / sqrtf(vv * (1.f / 64.f) + 1e-5f);
    s_tm[lane] = d * rstd * ln_w[lane] + ln_b[lane];
  }
  __syncthreads();

  // h2 = gelu(tm @ ng_w1.T + b1)  (128 outputs)
  if (t < 128) {
    float acc = ng_b1[t];
    const float* wr = ng_w1 + (size_t)t * 64;
#pragma unroll 16
    for (int m = 0; m < 64; ++m) acc += s_tm[m] * wr[m];
    s_h2[t] = gelu_exact(acc);
  }
  __syncthreads();

  // nm_pre: 2048 wave-dots of length 128 (128 per wave, float2 per lane)
  for (int it = 0; it < 128; ++it) {
    int o = wid * 128 + it;
    const float2 wv2 = *(const float2*)(ng_w2 + (size_t)o * 128 + lane * 2);
    const float2 hv2 = *(const float2*)(s_h2 + lane * 2);
    float acc = wv2.x * hv2.x + wv2.y * hv2.y;
#pragma unroll
    for (int off = 32; off; off >>= 1) acc += __shfl_xor(acc, off);
    if (lane == 0) s_nm[o] = acc + ng_b2[o];
  }
  __syncthreads();

  // LN per node (2 nodes per wave)
  for (int it = 0; it < 2; ++it) {
    int node = wid * 2 + it;
    float v = s_nm[node * 64 + lane];
    float sm = v;
#pragma unroll
    for (int off = 32; off; off >>= 1) sm += __shfl_xor(sm, off);
    float mu = sm * (1.f / 64.f);
    float d = v - mu;
    float vv = d * d;
#pragma unroll
    for (int off = 32; off; off >>= 1) vv += __shfl_xor(vv, off);
    float rstd = 1.f / sqrtf(vv * (1.f / 64.f) + 1e-5f);
    s_nm[node * 64 + lane] = d * rstd * ln_w[lane] + ln_b[lane];
  }
  __syncthreads();

  // complexity head
  {
    int i = t >> 5, r = t & 31;  // t < 1024
    float acc = cp_b1[r];
    const float* wr = cp_w1 + (size_t)r * 64;
#pragma unroll 8
    for (int m = 0; m < 64; ++m) acc += s_nm[i * 64 + m] * wr[m];
    s_c1[t] = gelu_exact(acc);
  }
  // edges stage 1: s_t[i][n] = sum_m nm[i][m]*ep[m][n]
#pragma unroll
  for (int oi = 0; oi < 2; ++oi) {
    int o = t + oi * 1024;
    int i = o >> 6, n = o & 63;
    float acc = 0.f;
#pragma unroll 8
    for (int m = 0; m < 64; ++m) acc += s_nm[i * 64 + m] * ep_w[m * 64 + n];
    s_t[o] = acc;
  }
  __syncthreads();
  if (t < 32) {
    float acc = cp_b2[0];
#pragma unroll 8
    for (int r = 0; r < 32; ++r) acc += s_c1[t * 32 + r] * cp_w2[r];
    float sp = softplus_f(acc);
    s_cx[t] = sp;
    out[OUT_CPLX + b * 32 + t] = sp;
    out[OUT_MASK + b * 32 + t] = 1.0f;
  }
  // edges stage 2: logits
  {
    int i = t >> 5, j = t & 31;
    float acc = ep_b[0];
#pragma unroll 8
    for (int n = 0; n < 64; ++n) acc += s_t[i * 64 + n] * s_nm[j * 64 + n];
    float sg = 1.f / (1.f + expf(-acc));
    float val = (j > i && sg > 0.3f) ? 1.f : 0.f;
    out[OUT_ADJ + (size_t)b * 1024 + i * 32 + j] = val;
  }
  __syncthreads();
  if (wid == 0) {
    float v = (lane < 32) ? s_cx[lane] : 0.f;
#pragma unroll
    for (int off = 32; off; off >>= 1) v += __shfl_xor(v, off);
    if (lane == 0) out[OUT_SURF + b] = v;
  }

  // nemb: e = t (full E across the block); w row cached in regs
  {
    float4 w[16];
    const float* wr = np_w + (size_t)t * 64;
#pragma unroll
    for (int k = 0; k < 16; ++k) w[k] = *(const float4*)(wr + k * 4);
    float bias = np_b[t];
    for (int i = 0; i < 32; ++i) {
      float acc = bias;
#pragma unroll
      for (int k = 0; k < 16; ++k)
        acc += dot4(w[k], *(const float4*)(s_nm + i * 64 + k * 4));
      out[OUT_EMB + (size_t)(b * 32 + i) * 1024 + t] = acc;
    }
  }
}

extern "C" void kernel_launch(void* const* d_in, const int* in_sizes, int n_in,
                              void* d_out, int out_size, void* d_ws, size_t ws_size,
                              hipStream_t stream) {
  (void)in_sizes; (void)n_in; (void)out_size; (void)ws_size;
  const float* x    = (const float*)d_in[0];
  const float* tq   = (const float*)d_in[1];
  const float* wq   = (const float*)d_in[2];
  const float* bq   = (const float*)d_in[3];
  const float* wk   = (const float*)d_in[4];
  const float* bk   = (const float*)d_in[5];
  const float* wv   = (const float*)d_in[6];
  const float* bv   = (const float*)d_in[7];
  const float* wo   = (const float*)d_in[8];
  const float* bo   = (const float*)d_in[9];
  const float* mp_w = (const float*)d_in[10];
  const float* mp_b = (const float*)d_in[11];
  const float* ln_w = (const float*)d_in[12];
  const float* ln_b = (const float*)d_in[13];
  const float* ng_w1 = (const float*)d_in[14];
  const float* ng_b1 = (const float*)d_in[15];
  const float* ng_w2 = (const float*)d_in[16];
  const float* ng_b2 = (const float*)d_in[17];
  const float* ep_w  = (const float*)d_in[20];
  const float* ep_b  = (const float*)d_in[21];
  const float* cp_w1 = (const float*)d_in[22];
  const float* cp_b1 = (const float*)d_in[23];
  const float* cp_w2 = (const float*)d_in[24];
  const float* cp_b2 = (const float*)d_in[25];
  const float* np_w  = (const float*)d_in[26];
  const float* np_b  = (const float*)d_in[27];

  float* out = (float*)d_out;
  float* ws = (float*)d_ws;
  float* qvec    = ws + OFF_QVEC;
  float* qkT     = ws + OFF_QKT;
  float* qb      = ws + OFF_QB;
  float* lpart   = ws + OFF_LPART;
  float* xa      = ws + OFF_XA;
  float* partial = ws + OFF_PART;

  k_qvec<<<256, 256, 0, stream>>>(tq, wq, bq, qvec);
  k_qk<<<32, 256, 0, stream>>>(qvec, wk, bk, qkT, qb);
  k_fused<<<512, 256, 0, stream>>>(x, qkT, qb, partial, lpart);
  k_comb2<<<128, 256, 0, stream>>>(partial, lpart, xa);
  k_tail<<<16, 1024, 0, stream>>>(xa, wv, bv, wo, bo, mp_w, mp_b, ln_w, ln_b,
                                  ng_w1, ng_b1, ng_w2, ng_b2, ep_w, ep_b,
                                  cp_w1, cp_b1, cp_w2, cp_b2, np_w, np_b, out);
}

// Round 7
// 178.275 us; speedup vs baseline: 2.3267x; 2.3267x over previous
//
#include <hip/hip_runtime.h>
#include <hip/hip_bf16.h>

// ForcedDAGPlanner: B=16,S=4096,E=1024,M=64,N=32,H=8,D=128
//   scores[b,h,s] = x[b,s,:]·qk[h,:] + qb[h]   (qk = (q·Wk)/sqrt(D), 8x1024)
//   xa[b,h,:]     = softmax-weighted sum of x rows (unnormalized partials + l)
//   ctx[b,j]      = xa[b,h(j),:]·wv[j,:] + bv[j]
//   k_nodes = 32 -> node_mask all-true.
// R7: r6 front-end (k_fused v4 ~40us, measured 52us incl gaps) + r5 parallel
// tail (r6 mega-tail was 363us: 16 blocks, 9MB weights/block, latency-bound).
// comb2+ctx merged; heads+nemb merged. 8 launches.

#define DEVFN __device__ __forceinline__

constexpr float SCALE = 0.08838834764831845f; // 1/sqrt(128)

// workspace offsets (floats)
constexpr size_t OFF_QVEC  = 0;        // 1024
constexpr size_t OFF_QKT   = 1024;     // 8192  [h*1024+e]
constexpr size_t OFF_QB    = 9216;     // 8
constexpr size_t OFF_LPART = 9224;     // 4096  [cid*8+h]
constexpr size_t OFF_CTX   = 13320;    // 16384
constexpr size_t OFF_TREP  = 29704;    // 16384
constexpr size_t OFF_TM    = 46088;    // 1024
constexpr size_t OFF_NMG   = 47112;    // 32768
constexpr size_t OFF_PART  = 79880;    // 512*8*1024 = 4194304 [cid][h][e]
// total ~17.1 MB of d_ws

// output offsets (f32 elements)
constexpr size_t OUT_EMB  = 0;        // 16*32*1024
constexpr size_t OUT_ADJ  = 524288;   // 16*32*32
constexpr size_t OUT_SURF = 540672;   // 16
constexpr size_t OUT_CPLX = 540688;   // 16*32
constexpr size_t OUT_MASK = 541200;   // 16*32

DEVFN float gelu_exact(float x) {
  return 0.5f * x * (1.0f + erff(x * 0.70710678118654752f));
}
DEVFN float softplus_f(float x) {
  return fmaxf(x, 0.0f) + log1pf(expf(-fabsf(x)));
}
DEVFN float dot4(float4 a, float4 b) {
  return a.x * b.x + a.y * b.y + a.z * b.z + a.w * b.w;
}

// ---- K0: qvec[i] = task_query · wq[i,:] + bq[i]   (wave per output)
__global__ void k_qvec(const float* __restrict__ tq, const float* __restrict__ wq,
                       const float* __restrict__ bq, float* __restrict__ qvec) {
  int wid = threadIdx.x >> 6, lane = threadIdx.x & 63;
  int i = blockIdx.x * 4 + wid;  // 256 blocks -> 1024 outputs
  const float* wrow = wq + (size_t)i * 1024;
  float acc = 0.f;
#pragma unroll
  for (int k = 0; k < 4; ++k) {
    int e = lane * 4 + k * 256;
    acc += dot4(*(const float4*)(tq + e), *(const float4*)(wrow + e));
  }
#pragma unroll
  for (int off = 32; off; off >>= 1) acc += __shfl_xor(acc, off);
  if (lane == 0) qvec[i] = acc + bq[i];
}

// ---- K0b: qkT[h*1024+e] = SCALE * sum_d qvec[h*128+d]*wk[(h*128+d)*1024+e]; qb[h]
__global__ void k_qk(const float* __restrict__ qvec, const float* __restrict__ wk,
                     const float* __restrict__ bk, float* __restrict__ qkT,
                     float* __restrict__ qb) {
  __shared__ float qh[128];
  int h = blockIdx.x >> 2, e0 = (blockIdx.x & 3) * 256;  // 32 blocks
  int t = threadIdx.x;
  if (t < 128) qh[t] = qvec[h * 128 + t];
  __syncthreads();
  int e = e0 + t;
  float acc = 0.f;
#pragma unroll 32
  for (int d = 0; d < 128; ++d)
    acc += qh[d] * wk[(size_t)(h * 128 + d) * 1024 + e];
  qkT[h * 1024 + e] = acc * SCALE;
  if (t == 0 && e0 == 0) {
    float s = 0.f;
    for (int d = 0; d < 128; ++d) s += qh[d] * bk[h * 128 + d];
    qb[h] = s * SCALE;
  }
}

// ---- K1 v4 (unchanged from R6): fused score+exp+weighted-sum, single x pass.
// 512 blocks x 256 threads; waves (rh,hg): rows [rh*64,+64), heads [hg*4,+4).
__global__ __launch_bounds__(256, 2) void k_fused(
    const float* __restrict__ x, const float* __restrict__ qkT,
    const float* __restrict__ qb, float* __restrict__ partial,
    float* __restrict__ lpart) {
  __shared__ __align__(16) float lds[8 * 1024];
  __shared__ float s_ll[8];
  int t = threadIdx.x, wid = t >> 6, lane = t & 63;
  int rh = wid >> 1, hg = wid & 1;

  float4 qr[4][4];
#pragma unroll
  for (int hh = 0; hh < 4; ++hh)
#pragma unroll
    for (int k = 0; k < 4; ++k)
      qr[hh][k] = *(const float4*)(qkT + (hg * 4 + hh) * 1024 + k * 256 + lane * 4);
  float qbr[4];
#pragma unroll
  for (int hh = 0; hh < 4; ++hh) qbr[hh] = qb[hg * 4 + hh];

  float4 acc[4][4];
#pragma unroll
  for (int hh = 0; hh < 4; ++hh)
#pragma unroll
    for (int k = 0; k < 4; ++k) acc[hh][k] = make_float4(0.f, 0.f, 0.f, 0.f);
  float lsum[4] = {0.f, 0.f, 0.f, 0.f};

  int row0 = blockIdx.x * 128 + rh * 64;
  const float* xr = x + ((size_t)row0 << 10) + lane * 4;
  float4 A0 = *(const float4*)(xr + 0);
  float4 A1 = *(const float4*)(xr + 256);
  float4 A2 = *(const float4*)(xr + 512);
  float4 A3 = *(const float4*)(xr + 768);
  float4 B0 = *(const float4*)(xr + 1024);
  float4 B1 = *(const float4*)(xr + 1280);
  float4 B2 = *(const float4*)(xr + 1536);
  float4 B3 = *(const float4*)(xr + 1792);

  for (int r = 0; r < 64; ++r) {
    float4 c0 = A0, c1 = A1, c2 = A2, c3 = A3;
    A0 = B0; A1 = B1; A2 = B2; A3 = B3;
    if (r < 62) {
      const float* nx = xr + ((size_t)(r + 2) << 10);
      B0 = *(const float4*)(nx + 0);
      B1 = *(const float4*)(nx + 256);
      B2 = *(const float4*)(nx + 512);
      B3 = *(const float4*)(nx + 768);
    }
    float s[4];
#pragma unroll
    for (int hh = 0; hh < 4; ++hh)
      s[hh] = dot4(c0, qr[hh][0]) + dot4(c1, qr[hh][1]) +
              dot4(c2, qr[hh][2]) + dot4(c3, qr[hh][3]);
#pragma unroll
    for (int off = 1; off <= 32; off <<= 1)
#pragma unroll
      for (int hh = 0; hh < 4; ++hh) s[hh] += __shfl_xor(s[hh], off);
    float w[4];
#pragma unroll
    for (int hh = 0; hh < 4; ++hh) {
      w[hh] = expf(s[hh] + qbr[hh]);
      lsum[hh] += w[hh];
    }
#pragma unroll
    for (int hh = 0; hh < 4; ++hh) {
      acc[hh][0].x += w[hh] * c0.x; acc[hh][0].y += w[hh] * c0.y;
      acc[hh][0].z += w[hh] * c0.z; acc[hh][0].w += w[hh] * c0.w;
      acc[hh][1].x += w[hh] * c1.x; acc[hh][1].y += w[hh] * c1.y;
      acc[hh][1].z += w[hh] * c1.z; acc[hh][1].w += w[hh] * c1.w;
      acc[hh][2].x += w[hh] * c2.x; acc[hh][2].y += w[hh] * c2.y;
      acc[hh][2].z += w[hh] * c2.z; acc[hh][2].w += w[hh] * c2.w;
      acc[hh][3].x += w[hh] * c3.x; acc[hh][3].y += w[hh] * c3.y;
      acc[hh][3].z += w[hh] * c3.z; acc[hh][3].w += w[hh] * c3.w;
    }
  }
  if (rh == 1) {
#pragma unroll
    for (int hh = 0; hh < 4; ++hh)
#pragma unroll
      for (int k = 0; k < 4; ++k)
        *(float4*)(lds + (hg * 4 + hh) * 1024 + k * 256 + lane * 4) = acc[hh][k];
    if (lane == 0)
#pragma unroll
      for (int hh = 0; hh < 4; ++hh) s_ll[hg * 4 + hh] = lsum[hh];
  }
  __syncthreads();
  if (rh == 0) {
    size_t base = (((size_t)blockIdx.x * 8 + hg * 4) << 10) + lane * 4;
#pragma unroll
    for (int hh = 0; hh < 4; ++hh)
#pragma unroll
      for (int k = 0; k < 4; ++k) {
        const float4 o = *(const float4*)(lds + (hg * 4 + hh) * 1024 + k * 256 + lane * 4);
        float4 v = acc[hh][k];
        v.x += o.x; v.y += o.y; v.z += o.z; v.w += o.w;
        *(float4*)(partial + base + ((size_t)hh << 10) + k * 256) = v;
      }
    if (lane == 0)
#pragma unroll
      for (int hh = 0; hh < 4; ++hh)
        lpart[blockIdx.x * 8 + hg * 4 + hh] = lsum[hh] + s_ll[hg * 4 + hh];
  }
}

// ---- K2: comb2+ctx fused. Block (b,h) of 128: reduce xa slice in LDS, then
// ctx[b, j in head h] = (xa_unnorm · wv[j,:]) * linv + bv[j]  (128 wave-dots)
__global__ __launch_bounds__(256) void k_combctx(
    const float* __restrict__ partial, const float* __restrict__ lpart,
    const float* __restrict__ wv, const float* __restrict__ bv,
    float* __restrict__ ctx) {
  __shared__ __align__(16) float s_xa[1024];
  __shared__ float s_linv;
  int bh = blockIdx.x, b = bh >> 3, h = bh & 7, t = threadIdx.x;
  float4 s4 = make_float4(0.f, 0.f, 0.f, 0.f);
#pragma unroll 8
  for (int c = 0; c < 32; ++c) {
    float4 v = *(const float4*)(partial +
        (((size_t)(b * 32 + c) * 8 + h) << 10) + t * 4);
    s4.x += v.x; s4.y += v.y; s4.z += v.z; s4.w += v.w;
  }
  *(float4*)(s_xa + t * 4) = s4;
  if (t == 0) {
    float s = 0.f;
#pragma unroll
    for (int c = 0; c < 32; ++c) s += lpart[(b * 32 + c) * 8 + h];
    s_linv = 1.0f / s;
  }
  __syncthreads();
  int wid = t >> 6, lane = t & 63;
  float linv = s_linv;
  for (int it = 0; it < 32; ++it) {
    int j = h * 128 + wid * 32 + it;
    const float* wr = wv + (size_t)j * 1024 + lane * 4;
    const float* xr = s_xa + lane * 4;
    float acc = 0.f;
#pragma unroll
    for (int k = 0; k < 4; ++k)
      acc += dot4(*(const float4*)(xr + k * 256), *(const float4*)(wr + k * 256));
#pragma unroll
    for (int off = 32; off; off >>= 1) acc += __shfl_xor(acc, off);
    if (lane == 0) ctx[b * 1024 + j] = acc * linv + bv[j];
  }
}

// ---- K3: task_repr[b*1024+i] = ctx[b,:]·wo[i,:] + bo[i]  (16 outputs/block)
__global__ void k_trep(const float* __restrict__ ctx, const float* __restrict__ wo,
                       const float* __restrict__ bo, float* __restrict__ trep) {
  int wid = threadIdx.x >> 6, lane = threadIdx.x & 63;
#pragma unroll
  for (int it = 0; it < 4; ++it) {
    int gw = blockIdx.x * 16 + wid * 4 + it;  // 1024 blocks
    int b = gw >> 10, i = gw & 1023;
    const float* xr = ctx + (size_t)b * 1024;
    const float* wr = wo + (size_t)i * 1024;
    float acc = 0.f;
#pragma unroll
    for (int k = 0; k < 4; ++k) {
      int e = lane * 4 + k * 256;
      acc += dot4(*(const float4*)(xr + e), *(const float4*)(wr + e));
    }
#pragma unroll
    for (int off = 32; off; off >>= 1) acc += __shfl_xor(acc, off);
    if (lane == 0) trep[b * 1024 + i] = acc + bo[i];
  }
}

// ---- K4: tm_pre[b*64+m] = trep[b,:]·mp_w[m,:] + mp_b[m]  (64 blocks)
__global__ void k_tm(const float* __restrict__ trep, const float* __restrict__ mp_w,
                     const float* __restrict__ mp_b, float* __restrict__ tmg) {
  int b = blockIdx.x >> 2, mc = blockIdx.x & 3;
  int wid = threadIdx.x >> 6, lane = threadIdx.x & 63;
  const float* xr = trep + (size_t)b * 1024 + lane * 4;
#pragma unroll
  for (int it = 0; it < 4; ++it) {
    int m = mc * 16 + wid * 4 + it;
    const float* wr = mp_w + (size_t)m * 1024 + lane * 4;
    float acc = 0.f;
#pragma unroll
    for (int k = 0; k < 4; ++k)
      acc += dot4(*(const float4*)(xr + k * 256), *(const float4*)(wr + k * 256));
#pragma unroll
    for (int off = 32; off; off >>= 1) acc += __shfl_xor(acc, off);
    if (lane == 0) tmg[b * 64 + m] = acc + mp_b[m];
  }
}

// ---- K5: per (b, node-pair): LN(tm) -> h2 -> nm_pre(2 nodes) -> LN -> nmg
// 256 blocks; LN+h2 recomputed redundantly per block (tiny).
__global__ __launch_bounds__(256) void k_nm(
    const float* __restrict__ tmg, const float* __restrict__ ln_w,
    const float* __restrict__ ln_b, const float* __restrict__ ng_w1,
    const float* __restrict__ ng_b1, const float* __restrict__ ng_w2,
    const float* __restrict__ ng_b2, float* __restrict__ nmg) {
  __shared__ float s_tm[64];
  __shared__ float s_h2[128];
  __shared__ float s_np[128];
  int b = blockIdx.x >> 4, np = blockIdx.x & 15;
  int t = threadIdx.x, wid = t >> 6, lane = t & 63;
  if (wid == 0) {
    float v = tmg[b * 64 + lane];
    float sm = v;
#pragma unroll
    for (int off = 32; off; off >>= 1) sm += __shfl_xor(sm, off);
    float mu = sm * (1.f / 64.f);
    float d = v - mu;
    float vv = d * d;
#pragma unroll
    for (int off = 32; off; off >>= 1) vv += __shfl_xor(vv, off);
    float rstd = 1.f / sqrtf(vv * (1.f / 64.f) + 1e-5f);
    s_tm[lane] = d * rstd * ln_w[lane] + ln_b[lane];
  }
  __syncthreads();
  if (t < 128) {
    float acc = ng_b1[t];
    const float* wr = ng_w1 + (size_t)t * 64;
#pragma unroll 16
    for (int m = 0; m < 64; ++m) acc += s_tm[m] * wr[m];
    s_h2[t] = gelu_exact(acc);
  }
  __syncthreads();
  if (t < 128) {
    int o = np * 128 + t;
    float acc = ng_b2[o];
    const float* wr = ng_w2 + (size_t)o * 128;
#pragma unroll 8
    for (int r = 0; r < 128; ++r) acc += s_h2[r] * wr[r];
    s_np[t] = acc;
  }
  __syncthreads();
  if (wid < 2) {
    float v = s_np[wid * 64 + lane];
    float sm = v;
#pragma unroll
    for (int off = 32; off; off >>= 1) sm += __shfl_xor(sm, off);
    float mu = sm * (1.f / 64.f);
    float d = v - mu;
    float vv = d * d;
#pragma unroll
    for (int off = 32; off; off >>= 1) vv += __shfl_xor(vv, off);
    float rstd = 1.f / sqrtf(vv * (1.f / 64.f) + 1e-5f);
    nmg[b * 2048 + (np * 2 + wid) * 64 + lane] = d * rstd * ln_w[lane] + ln_b[lane];
  }
}

// ---- K6: merged heads (blocks 0..15) + node embeddings (blocks 16..79)
__global__ __launch_bounds__(256) void k_headsemb(
    const float* __restrict__ nmg, const float* __restrict__ ep_w,
    const float* __restrict__ ep_b, const float* __restrict__ cp_w1,
    const float* __restrict__ cp_b1, const float* __restrict__ cp_w2,
    const float* __restrict__ cp_b2, const float* __restrict__ np_w,
    const float* __restrict__ np_b, float* __restrict__ out) {
  __shared__ __align__(16) float s_nm[2048];
  __shared__ float s_t[2048];
  __shared__ float s_c1[1024];
  __shared__ float s_cx[32];
  int t = threadIdx.x, wid = t >> 6, lane = t & 63;
  if (blockIdx.x < 16) {
    int b = blockIdx.x;
    for (int i = t; i < 512; i += 256)
      ((float4*)s_nm)[i] = ((const float4*)(nmg + (size_t)b * 2048))[i];
    __syncthreads();
    for (int o = t; o < 1024; o += 256) {
      int i = o >> 5, r = o & 31;
      float acc = cp_b1[r];
      const float* wr = cp_w1 + (size_t)r * 64;
#pragma unroll 8
      for (int m = 0; m < 64; ++m) acc += s_nm[i * 64 + m] * wr[m];
      s_c1[o] = gelu_exact(acc);
    }
    __syncthreads();
    if (t < 32) {
      float acc = cp_b2[0];
#pragma unroll 8
      for (int r = 0; r < 32; ++r) acc += s_c1[t * 32 + r] * cp_w2[r];
      float sp = softplus_f(acc);
      s_cx[t] = sp;
      out[OUT_CPLX + b * 32 + t] = sp;
      out[OUT_MASK + b * 32 + t] = 1.0f;
    }
    __syncthreads();
    if (wid == 0) {
      float v = (lane < 32) ? s_cx[lane] : 0.f;
#pragma unroll
      for (int off = 32; off; off >>= 1) v += __shfl_xor(v, off);
      if (lane == 0) out[OUT_SURF + b] = v;
    }
    for (int o = t; o < 2048; o += 256) {
      int i = o >> 6, n = o & 63;
      float acc = 0.f;
#pragma unroll 8
      for (int m = 0; m < 64; ++m) acc += s_nm[i * 64 + m] * ep_w[m * 64 + n];
      s_t[o] = acc;
    }
    __syncthreads();
    for (int o = t; o < 1024; o += 256) {
      int i = o >> 5, j = o & 31;
      float acc = ep_b[0];
#pragma unroll 8
      for (int n = 0; n < 64; ++n) acc += s_t[i * 64 + n] * s_nm[j * 64 + n];
      float sg = 1.f / (1.f + expf(-acc));
      float val = (j > i && sg > 0.3f) ? 1.f : 0.f;
      out[OUT_ADJ + (size_t)b * 1024 + i * 32 + j] = val;
    }
  } else {
    int idx = blockIdx.x - 16;  // 64 blocks
    int b = idx >> 2, e0 = (idx & 3) * 256;
    *(float4*)(s_nm + t * 4) = *(const float4*)(nmg + b * 2048 + t * 4);
    *(float4*)(s_nm + 1024 + t * 4) =
        *(const float4*)(nmg + b * 2048 + 1024 + t * 4);
    __syncthreads();
    int e = e0 + t;
    float4 w[16];
    const float* wr = np_w + (size_t)e * 64;
#pragma unroll
    for (int k = 0; k < 16; ++k) w[k] = *(const float4*)(wr + k * 4);
    float bias = np_b[e];
    for (int i = 0; i < 32; ++i) {
      float acc = bias;
#pragma unroll
      for (int k = 0; k < 16; ++k)
        acc += dot4(w[k], *(const float4*)(s_nm + i * 64 + k * 4));
      out[OUT_EMB + (size_t)(b * 32 + i) * 1024 + e] = acc;
    }
  }
}

extern "C" void kernel_launch(void* const* d_in, const int* in_sizes, int n_in,
                              void* d_out, int out_size, void* d_ws, size_t ws_size,
                              hipStream_t stream) {
  (void)in_sizes; (void)n_in; (void)out_size; (void)ws_size;
  const float* x    = (const float*)d_in[0];
  const float* tq   = (const float*)d_in[1];
  const float* wq   = (const float*)d_in[2];
  const float* bq   = (const float*)d_in[3];
  const float* wk   = (const float*)d_in[4];
  const float* bk   = (const float*)d_in[5];
  const float* wv   = (const float*)d_in[6];
  const float* bv   = (const float*)d_in[7];
  const float* wo   = (const float*)d_in[8];
  const float* bo   = (const float*)d_in[9];
  const float* mp_w = (const float*)d_in[10];
  const float* mp_b = (const float*)d_in[11];
  const float* ln_w = (const float*)d_in[12];
  const float* ln_b = (const float*)d_in[13];
  const float* ng_w1 = (const float*)d_in[14];
  const float* ng_b1 = (const float*)d_in[15];
  const float* ng_w2 = (const float*)d_in[16];
  const float* ng_b2 = (const float*)d_in[17];
  const float* ep_w  = (const float*)d_in[20];
  const float* ep_b  = (const float*)d_in[21];
  const float* cp_w1 = (const float*)d_in[22];
  const float* cp_b1 = (const float*)d_in[23];
  const float* cp_w2 = (const float*)d_in[24];
  const float* cp_b2 = (const float*)d_in[25];
  const float* np_w  = (const float*)d_in[26];
  const float* np_b  = (const float*)d_in[27];

  float* out = (float*)d_out;
  float* ws = (float*)d_ws;
  float* qvec    = ws + OFF_QVEC;
  float* qkT     = ws + OFF_QKT;
  float* qb      = ws + OFF_QB;
  float* lpart   = ws + OFF_LPART;
  float* ctx     = ws + OFF_CTX;
  float* trep    = ws + OFF_TREP;
  float* tmg     = ws + OFF_TM;
  float* nmg     = ws + OFF_NMG;
  float* partial = ws + OFF_PART;

  k_qvec<<<256, 256, 0, stream>>>(tq, wq, bq, qvec);
  k_qk<<<32, 256, 0, stream>>>(qvec, wk, bk, qkT, qb);
  k_fused<<<512, 256, 0, stream>>>(x, qkT, qb, partial, lpart);
  k_combctx<<<128, 256, 0, stream>>>(partial, lpart, wv, bv, ctx);
  k_trep<<<1024, 256, 0, stream>>>(ctx, wo, bo, trep);
  k_tm<<<64, 256, 0, stream>>>(trep, mp_w, mp_b, tmg);
  k_nm<<<256, 256, 0, stream>>>(tmg, ln_w, ln_b, ng_w1, ng_b1, ng_w2, ng_b2, nmg);
  k_headsemb<<<80, 256, 0, stream>>>(nmg, ep_w, ep_b, cp_w1, cp_b1, cp_w2,
                                     cp_b2, np_w, np_b, out);
}